// Round 18
// baseline (1573.975 us; speedup 1.0000x reference)
//
#include <hip/hip_runtime.h>
#include <math.h>

// Problem constants (B,S,H)=(4,1024,4096), NH=32, NKV=8, HD=128, LEVEL=256
#define B_   4
#define S_   1024
#define H_   4096
#define NH_  32
#define NKV_ 8
#define HD_  128
#define M_   (B_*S_)          // 4096 rows (b*S+s)
#define SCALING 0.08838834764831845f  // HD**-0.5

// ws regions (f16 units; total 48M f16 = 96 MB):
//   Qhi   [0,16M)    q packed [m][4096], rope-permuted dims
//   Qlo   [16M,32M)
//   Kfrag [32M,40M)  [b*8+kvh](2^18) [tile](2^12) [c](2^10) [hl](2^9) [lane*8+e]
//   Vt    [40M,44M)  flat [(b*8+kvh)*128+d][1024 ki], exact-int f16
//   PVint [0,16M)    (aliases Qhi, dead after attn) packed [m][4096]
//   WoHi  [16M,32M)  (aliases Qlo)   [n][4096]
//   WoLo  [32M,48M)  (aliases Kfrag+Vt+spare)
#define R16M 16777216

typedef _Float16 f16;
typedef __attribute__((ext_vector_type(4))) _Float16 f16x4;
typedef __attribute__((ext_vector_type(8))) _Float16 f16x8;
typedef __attribute__((ext_vector_type(4))) float f32x4;

__device__ __forceinline__ float lsq_sym(float x, float s) {
  float xs = x / s;
  xs = fminf(fmaxf(xs, -128.0f), 127.0f);
  return rintf(xs) * s;
}
__device__ __forceinline__ float lsq_asym(float x, float s) {
  float xs = x / s;
  xs = fminf(fmaxf(xs, 0.0f), 255.0f);
  return rintf(xs) * s;
}

struct f16pair { f16 hi, lo; };
__device__ __forceinline__ f16pair cvt_hilo(float x) {
  f16pair r;
  r.hi = (f16)x;
  r.lo = (f16)(x - (float)r.hi);
  return r;
}

__device__ __forceinline__ void gload16(const void* g, void* l) {
  __builtin_amdgcn_global_load_lds((const __attribute__((address_space(1))) void*)g,
                                   (__attribute__((address_space(3))) void*)l, 16, 0, 0);
}

// ---------------------------------------------------------------------------
// splits
// ---------------------------------------------------------------------------
__global__ __launch_bounds__(256)
void split_flat(const float* __restrict__ src, f16* __restrict__ hi, f16* __restrict__ lo)
{
  const size_t i = ((size_t)blockIdx.x * 256 + threadIdx.x) * 4;
  float4 v = *(const float4*)(src + i);
  f16x4 h, l; f16pair p;
  p = cvt_hilo(v.x); h.x = p.hi; l.x = p.lo;
  p = cvt_hilo(v.y); h.y = p.hi; l.y = p.lo;
  p = cvt_hilo(v.z); h.z = p.hi; l.z = p.lo;
  p = cvt_hilo(v.w); h.w = p.hi; l.w = p.lo;
  *(f16x4*)(hi + i) = h;
  *(f16x4*)(lo + i) = l;
}

// W rows permuted so RoPE pair (d, d+64) lands on adjacent output slots (2d, 2d+1)
__global__ __launch_bounds__(256)
void split_wqk(const float* __restrict__ W, f16* __restrict__ hi, f16* __restrict__ lo)
{
  const size_t i = ((size_t)blockIdx.x * 256 + threadIdx.x) * 4;
  const int n = (int)(i >> 12);
  const int k = (int)(i & 4095);
  const int d = n & 127;
  const int prow = (n & ~127) | ((d < 64) ? (d << 1) : (((d - 64) << 1) | 1));
  float4 v = *(const float4*)(W + i);
  f16x4 h, l; f16pair p;
  p = cvt_hilo(v.x); h.x = p.hi; l.x = p.lo;
  p = cvt_hilo(v.y); h.y = p.hi; l.y = p.lo;
  p = cvt_hilo(v.z); h.z = p.hi; l.z = p.lo;
  p = cvt_hilo(v.w); h.w = p.hi; l.w = p.lo;
  *(f16x4*)(hi + (size_t)prow * 4096 + k) = h;
  *(f16x4*)(lo + (size_t)prow * 4096 + k) = l;
}

// ---------------------------------------------------------------------------
// MFMA GEMM — BM x 128 tile, 4 waves, BK=32, global_load_lds staging,
// double-buffered, counted vmcnt (loads/wave/K-step = AIT*ATERMS + 4),
// s_setprio(1) around the MFMA cluster (T5: role-split waves exist here).
// lgkmcnt(0)+sched_barrier before trailing barrier (rules #18/#21).
// MFMA order per K-step identical to r14/r17 -> bit-identical accumulation.
// EPI 1: C[gr][gc] = lsq_sym(acc*(*sQp), *sKp)               (final out GEMM)
// EPI 5: fused QKV epilogue (region by n0: Q rope / K rope->Kfrag / V->Vt)
// ---------------------------------------------------------------------------
template<int BM, int ATERMS, int EPI>
__global__ __launch_bounds__(256, 2)
void gemm_mfma(const f16* __restrict__ Ahi, const f16* __restrict__ Alo, int lda,
               const f16* __restrict__ Bhi, const f16* __restrict__ Blo, int ldb,
               float* __restrict__ C, int ldc, int K,
               const float* __restrict__ sQp, const float* __restrict__ sKp,
               const float* __restrict__ sVp,
               const float* __restrict__ cosp, const float* __restrict__ sinp,
               f16* __restrict__ qhi, f16* __restrict__ qlo,
               f16* __restrict__ kfrag, f16* __restrict__ vt)
{
  constexpr int MI  = BM >> 5;   // acc rows: 4 (BM=128) or 8 (BM=256)
  constexpr int AIT = BM >> 6;   // A staging instrs/wave (per term): 2 or 4
  constexpr int ASZ = BM * 32;
  constexpr int BSZ = 128 * 32;
  constexpr int VMC = AIT * ATERMS + 4;   // loads/wave/K-step (prefetch in flight)

  __shared__ f16 sAh[2 * ASZ];
  __shared__ f16 sAl[(ATERMS == 2) ? 2 * ASZ : 64];
  __shared__ f16 sBh[2 * BSZ];
  __shared__ f16 sBl[2 * BSZ];

  const int m0 = blockIdx.y * BM;
  const int n0 = blockIdx.x << 7;
  const int t    = threadIdx.x;
  const int lane = t & 63;
  const int wv   = t >> 6;
  const int wm   = (wv >> 1) * (BM >> 1);
  const int wn   = (wv & 1) << 6;
  const int lrow = lane & 15;
  const int kg   = (lane >> 4) << 3;
  const int fsw  = (lrow & 3) << 3;

  const int sr   = lane >> 2;
  const int slot = lane & 3;
  const int kcs  = ((slot ^ (sr & 3)) << 3);

  auto STAGE = [&](int kt, int buf) {
    const int k0 = kt << 5;
    const int ao = buf * ASZ, bo = buf * BSZ;
    #pragma unroll
    for (int i = 0; i < AIT; ++i) {
      const int rowb = wv * (BM >> 2) + (i << 4);
      const size_t goff = (size_t)(m0 + rowb + sr) * lda + k0 + kcs;
      gload16(Ahi + goff, &sAh[ao + rowb * 32]);
      if constexpr (ATERMS == 2) gload16(Alo + goff, &sAl[ao + rowb * 32]);
    }
    #pragma unroll
    for (int i = 0; i < 2; ++i) {
      const int rowb = (wv << 5) + (i << 4);
      const size_t goff = (size_t)(n0 + rowb + sr) * ldb + k0 + kcs;
      gload16(Bhi + goff, &sBh[bo + rowb * 32]);
      gload16(Blo + goff, &sBl[bo + rowb * 32]);
    }
  };

  f32x4 acc[MI][4];
  #pragma unroll
  for (int i = 0; i < MI; ++i)
    #pragma unroll
    for (int j = 0; j < 4; ++j) acc[i][j] = (f32x4){0.f, 0.f, 0.f, 0.f};

  const int T = K >> 5;
  STAGE(0, 0);

  for (int kt = 0; kt < T; ++kt) {
    const int cur = kt & 1;
    if (kt + 1 < T) {
      STAGE(kt + 1, cur ^ 1);
      if constexpr (VMC == 8)
        asm volatile("s_waitcnt vmcnt(8)" ::: "memory");  // tile kt landed; next 8 in flight
      else
        asm volatile("s_waitcnt vmcnt(6)" ::: "memory");  // tile kt landed; next 6 in flight
    } else {
      asm volatile("s_waitcnt vmcnt(0)" ::: "memory");
    }
    __builtin_amdgcn_sched_barrier(0);
    asm volatile("s_barrier" ::: "memory");              // all waves' tile-kt loads visible

    const int ao = cur * ASZ, bo = cur * BSZ;
    f16x8 a[MI], bh[4], bl[4];
    #pragma unroll
    for (int j = 0; j < 4; ++j) {
      const int r = wn + (j << 4) + lrow;
      bh[j] = *(const f16x8*)&sBh[bo + r * 32 + (kg ^ fsw)];
      bl[j] = *(const f16x8*)&sBl[bo + r * 32 + (kg ^ fsw)];
    }
    #pragma unroll
    for (int i = 0; i < MI; ++i)
      a[i] = *(const f16x8*)&sAh[ao + (wm + (i << 4) + lrow) * 32 + (kg ^ fsw)];
    __builtin_amdgcn_s_setprio(1);
    #pragma unroll
    for (int i = 0; i < MI; ++i)
      #pragma unroll
      for (int j = 0; j < 4; ++j) {
        acc[i][j] = __builtin_amdgcn_mfma_f32_16x16x32_f16(a[i], bh[j], acc[i][j], 0, 0, 0);
        acc[i][j] = __builtin_amdgcn_mfma_f32_16x16x32_f16(a[i], bl[j], acc[i][j], 0, 0, 0);
      }
    __builtin_amdgcn_s_setprio(0);
    if constexpr (ATERMS == 2) {
      #pragma unroll
      for (int i = 0; i < MI; ++i)
        a[i] = *(const f16x8*)&sAl[ao + (wm + (i << 4) + lrow) * 32 + (kg ^ fsw)];
      __builtin_amdgcn_s_setprio(1);
      #pragma unroll
      for (int i = 0; i < MI; ++i)
        #pragma unroll
        for (int j = 0; j < 4; ++j)
          acc[i][j] = __builtin_amdgcn_mfma_f32_16x16x32_f16(a[i], bh[j], acc[i][j], 0, 0, 0);
      __builtin_amdgcn_s_setprio(0);
    }

    asm volatile("s_waitcnt lgkmcnt(0)" ::: "memory");   // ds_reads retired
    __builtin_amdgcn_sched_barrier(0);
    asm volatile("s_barrier" ::: "memory");              // safe to overwrite buf next iter
  }

  // region / scale selection (block-uniform: n0 per-block, tiles never straddle)
  int region = 0;
  float s, sQv = 1.0f;
  if constexpr (EPI == 1) {
    s = *sQp; sQv = *sKp;                 // s_after, s_o
  } else {
    region = (n0 < 4096) ? 0 : ((n0 < 5120) ? 1 : 2);
    s = (region == 0) ? *sQp : (region == 1) ? *sKp : *sVp;
  }

  #pragma unroll
  for (int i = 0; i < MI; ++i)
    #pragma unroll
    for (int j = 0; j < 4; ++j) {
      const int gc = n0 + wn + (j << 4) + lrow;
      #pragma unroll
      for (int r = 0; r < 4; ++r) {
        const int gr = m0 + wm + (i << 4) + ((lane >> 4) << 2) + r;
        float x = acc[i][j][r];
        if constexpr (EPI == 1) {
          C[(size_t)gr * ldc + gc] = lsq_sym(x * s, sQv);
        } else {
          if (region <= 1) {
            float qv = lsq_sym(x, s);
            float pv = __shfl_xor(qv, 1);
            const int dperm = gc & 127;
            const int dpair = dperm >> 1;
            float cs = cosp[(size_t)gr * HD_ + dpair];
            float sn = sinp[(size_t)gr * HD_ + dpair];
            float ro = (gc & 1) ? (qv * cs + pv * sn) : (qv * cs - pv * sn);
            f16pair hp = cvt_hilo(ro);
            if (region == 0) {
              qhi[(size_t)gr * 4096 + gc] = hp.hi;
              qlo[(size_t)gr * 4096 + gc] = hp.lo;
            } else {
              const int lcol = gc - 4096;
              const int bb = gr >> 10, ki = gr & 1023;
              const int kvh = lcol >> 7;
              const int c = dperm >> 5, sub = (dperm >> 3) & 3, e = dperm & 7;
              const size_t base = ((size_t)(bb * 8 + kvh) << 18) + ((size_t)(ki >> 4) << 12)
                                + (c << 10) + ((ki & 15) << 3) + (sub << 7) + e;
              kfrag[base] = hp.hi;
              kfrag[base + 512] = hp.lo;
            }
          } else {
            float xi = rintf(fminf(fmaxf(x / s, -128.0f), 127.0f));
            const int lcol = gc - 5120;
            const int bb = gr >> 10, ss = gr & 1023;
            const int kv = lcol >> 7, dd = lcol & 127;
            vt[(((size_t)(bb * 8 + kv) * 128 + dd) << 10) + ss] = (f16)xi;
          }
        }
      }
    }
}

// ---------------------------------------------------------------------------
// Fused scores+quant+mask+softmax: 16 q-rows/block, 4 waves, swapped mfma(K,Q):
// D[ki][qi], lane -> qi = qi0+(lane&15), ki = tile*16 + (lane>>4)*4 + r.
// K loaded from Kfrag: 1KB contiguous per wave instruction. float4 stores.
// ---------------------------------------------------------------------------
__global__ __launch_bounds__(256)
void attn_fused(const f16* __restrict__ qhiB, const f16* __restrict__ qloB,
                const f16* __restrict__ kfrag, float* __restrict__ attn,
                const float* __restrict__ saP)
{
  const int b = blockIdx.z, h = blockIdx.y, qi0 = blockIdx.x << 4;
  const int t = threadIdx.x, lane = t & 63, w = t >> 6;   // w in 0..3
  const int lc = lane & 15, lg = lane >> 4;
  const int kvh = h >> 2;
  const float sa = *saP;

  f16x8 qh[4], ql[4];
  {
    const size_t qoff = (size_t)(b * S_ + qi0 + lc) * 4096 + h * HD_;
    #pragma unroll
    for (int c = 0; c < 4; ++c) {
      const int off = c * 32 + lg * 8;
      qh[c] = *(const f16x8*)(qhiB + qoff + off);
      ql[c] = *(const f16x8*)(qloB + qoff + off);
    }
  }

  f32x4 acc[16];
  #pragma unroll
  for (int tt = 0; tt < 16; ++tt) acc[tt] = (f32x4){0.f, 0.f, 0.f, 0.f};

  const int qimax = qi0 + 15;
  const f16* kb = kfrag + ((size_t)(b * 8 + kvh) << 18);

  #pragma unroll
  for (int tt = 0; tt < 16; ++tt) {
    const int ki0 = (w << 8) + (tt << 4);
    if (ki0 <= qimax) {
      const f16* kt = kb + ((size_t)((w << 4) + tt) << 12) + lane * 8;
      #pragma unroll
      for (int c = 0; c < 4; ++c) {
        f16x8 kh = *(const f16x8*)(kt + (c << 10));
        f16x8 kl = *(const f16x8*)(kt + (c << 10) + 512);
        acc[tt] = __builtin_amdgcn_mfma_f32_16x16x32_f16(kh, qh[c], acc[tt], 0, 0, 0);
        acc[tt] = __builtin_amdgcn_mfma_f32_16x16x32_f16(kh, ql[c], acc[tt], 0, 0, 0);
        acc[tt] = __builtin_amdgcn_mfma_f32_16x16x32_f16(kl, qh[c], acc[tt], 0, 0, 0);
      }
    }
  }

  const int qi = qi0 + lc;

  float m = -3.0e38f;
  #pragma unroll
  for (int tt = 0; tt < 16; ++tt) {
    const int kib = (w << 8) + (tt << 4) + (lg << 2);
    #pragma unroll
    for (int r = 0; r < 4; ++r) {
      float x = (kib + r <= qi) ? lsq_asym(acc[tt][r] * SCALING, sa) : -3.0e38f;
      acc[tt][r] = x;
      m = fmaxf(m, x);
    }
  }
  m = fmaxf(m, __shfl_xor(m, 16));
  m = fmaxf(m, __shfl_xor(m, 32));

  __shared__ float redM[4][16];
  __shared__ float redS[4][16];
  if (lg == 0) redM[w][lc] = m;
  __syncthreads();
  float mrow = fmaxf(fmaxf(redM[0][lc], redM[1][lc]), fmaxf(redM[2][lc], redM[3][lc]));

  float ssum = 0.f;
  #pragma unroll
  for (int tt = 0; tt < 16; ++tt) {
    #pragma unroll
    for (int r = 0; r < 4; ++r) {
      float p = __expf(acc[tt][r] - mrow);
      acc[tt][r] = p;
      ssum += p;
    }
  }
  ssum += __shfl_xor(ssum, 16);
  ssum += __shfl_xor(ssum, 32);
  if (lg == 0) redS[w][lc] = ssum;
  __syncthreads();
  const float inv = 1.0f / (redS[0][lc] + redS[1][lc] + redS[2][lc] + redS[3][lc]);

  float* orow = attn + ((size_t)(b * NH_ + h) * S_ + qi) * S_ + (w << 8) + (lg << 2);
  #pragma unroll
  for (int tt = 0; tt < 16; ++tt) {
    float4 v;
    v.x = acc[tt][0] * inv;
    v.y = acc[tt][1] * inv;
    v.z = acc[tt][2] * inv;
    v.w = acc[tt][3] * inv;
    *(float4*)(orow + (tt << 4)) = v;
  }
}

// ---------------------------------------------------------------------------
// PV via MFMA: D'[d][q] = sum_ki Vt[d][ki] * P[q][ki]  (= (P·V)^T).
// A = Vt (exact int f16, 1 term); B = P rows, hi/lo split in-regs (2 terms).
// Epilogue: PVint = round(clip(s_v*acc/s_after,0,255)) exact f16, packed [m][4096].
// ---------------------------------------------------------------------------
__global__ __launch_bounds__(256)
void pv_mfma(const float* __restrict__ attn, const f16* __restrict__ vt,
             f16* __restrict__ pvint,
             const float* __restrict__ svP, const float* __restrict__ safP)
{
  const int b = blockIdx.z, h = blockIdx.y, q0 = blockIdx.x << 7;
  const int t = threadIdx.x, lane = t & 63, w = t >> 6;
  const int wd = (w >> 1) << 6, wq = (w & 1) << 6;
  const int lc = lane & 15, lg = lane >> 4;
  const int kvh = h >> 2;
  const float sv = *svP, saf = *safP;

  f32x4 acc[4][4];
  #pragma unroll
  for (int i = 0; i < 4; ++i)
    #pragma unroll
    for (int j = 0; j < 4; ++j) acc[i][j] = (f32x4){0.f, 0.f, 0.f, 0.f};

  const float* Pbase = attn + (size_t)(b * NH_ + h) * S_ * S_;
  const int kimax = q0 + 128;

  for (int ki0 = 0; ki0 < kimax; ki0 += 32) {
    f16x8 a[4];
    #pragma unroll
    for (int i = 0; i < 4; ++i) {
      const int d = wd + i * 16 + lc;
      a[i] = *(const f16x8*)(vt + (((size_t)(b * 8 + kvh) * 128 + d) << 10) + ki0 + lg * 8);
    }
    #pragma unroll
    for (int j = 0; j < 4; ++j) {
      const int q = q0 + wq + j * 16 + lc;
      const float* pp = Pbase + (size_t)q * S_ + ki0 + lg * 8;
      float4 p0 = *(const float4*)pp;
      float4 p1 = *(const float4*)(pp + 4);
      f16x8 bh, bl; f16pair pr;
      pr = cvt_hilo(p0.x); bh[0] = pr.hi; bl[0] = pr.lo;
      pr = cvt_hilo(p0.y); bh[1] = pr.hi; bl[1] = pr.lo;
      pr = cvt_hilo(p0.z); bh[2] = pr.hi; bl[2] = pr.lo;
      pr = cvt_hilo(p0.w); bh[3] = pr.hi; bl[3] = pr.lo;
      pr = cvt_hilo(p1.x); bh[4] = pr.hi; bl[4] = pr.lo;
      pr = cvt_hilo(p1.y); bh[5] = pr.hi; bl[5] = pr.lo;
      pr = cvt_hilo(p1.z); bh[6] = pr.hi; bl[6] = pr.lo;
      pr = cvt_hilo(p1.w); bh[7] = pr.hi; bl[7] = pr.lo;
      #pragma unroll
      for (int i = 0; i < 4; ++i) {
        acc[i][j] = __builtin_amdgcn_mfma_f32_16x16x32_f16(a[i], bh, acc[i][j], 0, 0, 0);
        acc[i][j] = __builtin_amdgcn_mfma_f32_16x16x32_f16(a[i], bl, acc[i][j], 0, 0, 0);
      }
    }
  }

  #pragma unroll
  for (int i = 0; i < 4; ++i)
    #pragma unroll
    for (int j = 0; j < 4; ++j) {
      const int q  = q0 + wq + j * 16 + lc;
      const int d0 = wd + i * 16 + lg * 4;
      f16x4 v;
      #pragma unroll
      for (int r = 0; r < 4; ++r) {
        float x = sv * acc[i][j][r];
        x = fminf(fmaxf(x / saf, 0.0f), 255.0f);
        v[r] = (f16)rintf(x);
      }
      *(f16x4*)(pvint + (size_t)(b * S_ + q) * 4096 + h * HD_ + d0) = v;
    }
}

extern "C" void kernel_launch(void* const* d_in, const int* in_sizes, int n_in,
                              void* d_out, int out_size, void* d_ws, size_t ws_size,
                              hipStream_t stream)
{
  const float* hidden = (const float*)d_in[0];
  const float* cosp   = (const float*)d_in[1];
  const float* sinp   = (const float*)d_in[2];
  const float* Wq     = (const float*)d_in[4];
  const float* Wk     = (const float*)d_in[5];
  const float* Wv     = (const float*)d_in[6];
  const float* Wo     = (const float*)d_in[7];
  const float* s_q    = (const float*)d_in[8];
  const float* s_k    = (const float*)d_in[9];
  const float* s_v    = (const float*)d_in[10];
  const float* s_attn = (const float*)d_in[11];
  const float* s_after= (const float*)d_in[12];
  const float* s_o    = (const float*)d_in[13];

  float* out  = (float*)d_out;                 // (B,S,H) f32
  float* attn = out + (size_t)M_ * H_;         // (B,NH,S,S) f32 — written by attn_fused

  f16* wsf   = (f16*)d_ws;
  f16* Qhi   = wsf;                    // [0,16M)
  f16* Qlo   = wsf + (size_t)R16M;     // [16M,32M)
  f16* Kfrag = wsf + (size_t)2*R16M;   // [32M,40M)
  f16* Vt    = wsf + (size_t)2*R16M + (size_t)R16M/2;  // [40M,44M)
  f16* PVint = wsf;                    // alias Qhi (dead after attn)
  f16* WoHi  = wsf + (size_t)R16M;     // alias Qlo
  f16* WoLo  = wsf + (size_t)2*R16M;   // alias Kfrag/Vt/spare

  // split scratch inside the not-yet-written attn region (~168 MB of 537)
  f16* scr = (f16*)attn;
  f16* hHi   = scr;                                  // hidden hi [0,16M)
  f16* hLo   = scr + (size_t)R16M;                   // hidden lo
  f16* WcatH = scr + (size_t)2*R16M;                 // [6144][4096] hi (24M f16)
  f16* WcatL = scr + (size_t)2*R16M + (size_t)6144*4096;  // lo

  dim3 blk(256, 1, 1);

  // 1) splits: hidden; Wq (rope-perm) -> rows [0,4096); Wk (rope-perm) -> rows
  //    [4096,5120); Wv (plain) -> rows [5120,6144) of Wcat
  split_flat<<<dim3(16384), blk, 0, stream>>>(hidden, hHi, hLo);
  split_wqk <<<dim3(16384), blk, 0, stream>>>(Wq, WcatH, WcatL);
  split_wqk <<<dim3(4096),  blk, 0, stream>>>(Wk, WcatH + (size_t)4096*4096, WcatL + (size_t)4096*4096);
  split_flat<<<dim3(4096),  blk, 0, stream>>>(Wv, WcatH + (size_t)5120*4096, WcatL + (size_t)5120*4096);

  // 2) ONE fused QKV projection GEMM (128^2 tiles, counted-vmcnt pipeline + setprio)
  gemm_mfma<128,2,5><<<dim3(48,32), blk, 0, stream>>>(hHi, hLo, H_, WcatH, WcatL, H_,
      nullptr, 0, H_, s_q, s_k, s_v, cosp, sinp, Qhi, Qlo, Kfrag, Vt);

  // 3) fused scores+quant+mask+softmax -> probs straight to d_out
  attn_fused<<<dim3(64, NH_, B_), blk, 0, stream>>>(Qhi, Qlo, Kfrag, attn, s_attn);

  // 4) PV (MFMA) -> PVint packed [m][4096]
  pv_mfma<<<dim3(8, NH_, B_), blk, 0, stream>>>(attn, Vt, PVint, s_v, s_after);

  // 5) Wo split (packed); final GEMM (128^2 tiles: grid 32x32=1024 blocks, 4/CU)
  split_flat<<<dim3(16384), blk, 0, stream>>>(Wo, WoHi, WoLo);
  gemm_mfma<128,1,1><<<dim3(32,32), blk, 0, stream>>>(PVint, nullptr, 4096,
      WoHi, WoLo, 4096, out, H_, H_, s_after, s_o, nullptr, nullptr, nullptr,
      nullptr, nullptr, nullptr, nullptr);
}

// Round 19
// 1495.224 us; speedup vs baseline: 1.0527x; 1.0527x over previous
//
#include <hip/hip_runtime.h>
#include <math.h>

// Problem constants (B,S,H)=(4,1024,4096), NH=32, NKV=8, HD=128, LEVEL=256
#define B_   4
#define S_   1024
#define H_   4096
#define NH_  32
#define NKV_ 8
#define HD_  128
#define M_   (B_*S_)          // 4096 rows (b*S+s)
#define SCALING 0.08838834764831845f  // HD**-0.5

// ws regions (f16 units; total 48M f16 = 96 MB):
//   Qhi   [0,16M)    q packed [m][4096], rope-permuted dims
//   Qlo   [16M,32M)
//   Kfrag [32M,40M)  [b*8+kvh](2^18) [tile](2^12) [c](2^10) [hl](2^9) [lane*8+e]
//   Vt    [40M,44M)  flat [(b*8+kvh)*128+d][1024 ki], exact-int f16
//   PVint [0,16M)    (aliases Qhi, dead after attn) packed [m][4096]
//   WoHi  [16M,32M)  (aliases Qlo)   [n][4096]
//   WoLo  [32M,48M)  (aliases Kfrag+Vt+spare)
#define R16M 16777216

typedef _Float16 f16;
typedef __attribute__((ext_vector_type(4))) _Float16 f16x4;
typedef __attribute__((ext_vector_type(8))) _Float16 f16x8;
typedef __attribute__((ext_vector_type(4))) float f32x4;

__device__ __forceinline__ float lsq_sym(float x, float s) {
  float xs = x / s;
  xs = fminf(fmaxf(xs, -128.0f), 127.0f);
  return rintf(xs) * s;
}
__device__ __forceinline__ float lsq_asym(float x, float s) {
  float xs = x / s;
  xs = fminf(fmaxf(xs, 0.0f), 255.0f);
  return rintf(xs) * s;
}

struct f16pair { f16 hi, lo; };
__device__ __forceinline__ f16pair cvt_hilo(float x) {
  f16pair r;
  r.hi = (f16)x;
  r.lo = (f16)(x - (float)r.hi);
  return r;
}

__device__ __forceinline__ void gload16(const void* g, void* l) {
  __builtin_amdgcn_global_load_lds((const __attribute__((address_space(1))) void*)g,
                                   (__attribute__((address_space(3))) void*)l, 16, 0, 0);
}

// ---------------------------------------------------------------------------
// splits
// ---------------------------------------------------------------------------
__global__ __launch_bounds__(256)
void split_flat(const float* __restrict__ src, f16* __restrict__ hi, f16* __restrict__ lo)
{
  const size_t i = ((size_t)blockIdx.x * 256 + threadIdx.x) * 4;
  float4 v = *(const float4*)(src + i);
  f16x4 h, l; f16pair p;
  p = cvt_hilo(v.x); h.x = p.hi; l.x = p.lo;
  p = cvt_hilo(v.y); h.y = p.hi; l.y = p.lo;
  p = cvt_hilo(v.z); h.z = p.hi; l.z = p.lo;
  p = cvt_hilo(v.w); h.w = p.hi; l.w = p.lo;
  *(f16x4*)(hi + i) = h;
  *(f16x4*)(lo + i) = l;
}

// W rows permuted so RoPE pair (d, d+64) lands on adjacent output slots (2d, 2d+1)
__global__ __launch_bounds__(256)
void split_wqk(const float* __restrict__ W, f16* __restrict__ hi, f16* __restrict__ lo)
{
  const size_t i = ((size_t)blockIdx.x * 256 + threadIdx.x) * 4;
  const int n = (int)(i >> 12);
  const int k = (int)(i & 4095);
  const int d = n & 127;
  const int prow = (n & ~127) | ((d < 64) ? (d << 1) : (((d - 64) << 1) | 1));
  float4 v = *(const float4*)(W + i);
  f16x4 h, l; f16pair p;
  p = cvt_hilo(v.x); h.x = p.hi; l.x = p.lo;
  p = cvt_hilo(v.y); h.y = p.hi; l.y = p.lo;
  p = cvt_hilo(v.z); h.z = p.hi; l.z = p.lo;
  p = cvt_hilo(v.w); h.w = p.hi; l.w = p.lo;
  *(f16x4*)(hi + (size_t)prow * 4096 + k) = h;
  *(f16x4*)(lo + (size_t)prow * 4096 + k) = l;
}

// ---------------------------------------------------------------------------
// MFMA GEMM — BM x 128 tile, 4 waves, BK=32, global_load_lds staging,
// double-buffered, counted vmcnt (loads/wave/K-step = AIT*ATERMS + 4),
// s_setprio(1) around the MFMA cluster (measured null-to-mild-positive here).
// lgkmcnt(0)+sched_barrier before trailing barrier (rules #18/#21).
// MFMA order per K-step identical to r14/r17 -> bit-identical accumulation.
// EPI 1: C[gr][gc] = lsq_sym(acc*(*sQp), *sKp)               (final out GEMM)
// EPI 5: fused QKV epilogue (region by n0: Q rope / K rope->Kfrag / V->Vt)
// ---------------------------------------------------------------------------
template<int BM, int ATERMS, int EPI>
__global__ __launch_bounds__(256, 2)
void gemm_mfma(const f16* __restrict__ Ahi, const f16* __restrict__ Alo, int lda,
               const f16* __restrict__ Bhi, const f16* __restrict__ Blo, int ldb,
               float* __restrict__ C, int ldc, int K,
               const float* __restrict__ sQp, const float* __restrict__ sKp,
               const float* __restrict__ sVp,
               const float* __restrict__ cosp, const float* __restrict__ sinp,
               f16* __restrict__ qhi, f16* __restrict__ qlo,
               f16* __restrict__ kfrag, f16* __restrict__ vt)
{
  constexpr int MI  = BM >> 5;   // acc rows: 4 (BM=128) or 8 (BM=256)
  constexpr int AIT = BM >> 6;   // A staging instrs/wave (per term): 2 or 4
  constexpr int ASZ = BM * 32;
  constexpr int BSZ = 128 * 32;
  constexpr int VMC = AIT * ATERMS + 4;   // loads/wave/K-step (prefetch in flight)

  __shared__ f16 sAh[2 * ASZ];
  __shared__ f16 sAl[(ATERMS == 2) ? 2 * ASZ : 64];
  __shared__ f16 sBh[2 * BSZ];
  __shared__ f16 sBl[2 * BSZ];

  const int m0 = blockIdx.y * BM;
  const int n0 = blockIdx.x << 7;
  const int t    = threadIdx.x;
  const int lane = t & 63;
  const int wv   = t >> 6;
  const int wm   = (wv >> 1) * (BM >> 1);
  const int wn   = (wv & 1) << 6;
  const int lrow = lane & 15;
  const int kg   = (lane >> 4) << 3;
  const int fsw  = (lrow & 3) << 3;

  const int sr   = lane >> 2;
  const int slot = lane & 3;
  const int kcs  = ((slot ^ (sr & 3)) << 3);

  auto STAGE = [&](int kt, int buf) {
    const int k0 = kt << 5;
    const int ao = buf * ASZ, bo = buf * BSZ;
    #pragma unroll
    for (int i = 0; i < AIT; ++i) {
      const int rowb = wv * (BM >> 2) + (i << 4);
      const size_t goff = (size_t)(m0 + rowb + sr) * lda + k0 + kcs;
      gload16(Ahi + goff, &sAh[ao + rowb * 32]);
      if constexpr (ATERMS == 2) gload16(Alo + goff, &sAl[ao + rowb * 32]);
    }
    #pragma unroll
    for (int i = 0; i < 2; ++i) {
      const int rowb = (wv << 5) + (i << 4);
      const size_t goff = (size_t)(n0 + rowb + sr) * ldb + k0 + kcs;
      gload16(Bhi + goff, &sBh[bo + rowb * 32]);
      gload16(Blo + goff, &sBl[bo + rowb * 32]);
    }
  };

  f32x4 acc[MI][4];
  #pragma unroll
  for (int i = 0; i < MI; ++i)
    #pragma unroll
    for (int j = 0; j < 4; ++j) acc[i][j] = (f32x4){0.f, 0.f, 0.f, 0.f};

  const int T = K >> 5;
  STAGE(0, 0);

  for (int kt = 0; kt < T; ++kt) {
    const int cur = kt & 1;
    if (kt + 1 < T) {
      STAGE(kt + 1, cur ^ 1);
      if constexpr (VMC == 8)
        asm volatile("s_waitcnt vmcnt(8)" ::: "memory");  // tile kt landed; next 8 in flight
      else
        asm volatile("s_waitcnt vmcnt(6)" ::: "memory");  // tile kt landed; next 6 in flight
    } else {
      asm volatile("s_waitcnt vmcnt(0)" ::: "memory");
    }
    __builtin_amdgcn_sched_barrier(0);
    asm volatile("s_barrier" ::: "memory");              // all waves' tile-kt loads visible

    const int ao = cur * ASZ, bo = cur * BSZ;
    f16x8 a[MI], bh[4], bl[4];
    #pragma unroll
    for (int j = 0; j < 4; ++j) {
      const int r = wn + (j << 4) + lrow;
      bh[j] = *(const f16x8*)&sBh[bo + r * 32 + (kg ^ fsw)];
      bl[j] = *(const f16x8*)&sBl[bo + r * 32 + (kg ^ fsw)];
    }
    #pragma unroll
    for (int i = 0; i < MI; ++i)
      a[i] = *(const f16x8*)&sAh[ao + (wm + (i << 4) + lrow) * 32 + (kg ^ fsw)];
    __builtin_amdgcn_s_setprio(1);
    #pragma unroll
    for (int i = 0; i < MI; ++i)
      #pragma unroll
      for (int j = 0; j < 4; ++j) {
        acc[i][j] = __builtin_amdgcn_mfma_f32_16x16x32_f16(a[i], bh[j], acc[i][j], 0, 0, 0);
        acc[i][j] = __builtin_amdgcn_mfma_f32_16x16x32_f16(a[i], bl[j], acc[i][j], 0, 0, 0);
      }
    __builtin_amdgcn_s_setprio(0);
    if constexpr (ATERMS == 2) {
      #pragma unroll
      for (int i = 0; i < MI; ++i)
        a[i] = *(const f16x8*)&sAl[ao + (wm + (i << 4) + lrow) * 32 + (kg ^ fsw)];
      __builtin_amdgcn_s_setprio(1);
      #pragma unroll
      for (int i = 0; i < MI; ++i)
        #pragma unroll
        for (int j = 0; j < 4; ++j)
          acc[i][j] = __builtin_amdgcn_mfma_f32_16x16x32_f16(a[i], bh[j], acc[i][j], 0, 0, 0);
      __builtin_amdgcn_s_setprio(0);
    }

    asm volatile("s_waitcnt lgkmcnt(0)" ::: "memory");   // ds_reads retired
    __builtin_amdgcn_sched_barrier(0);
    asm volatile("s_barrier" ::: "memory");              // safe to overwrite buf next iter
  }

  // region / scale selection (block-uniform: n0 per-block, tiles never straddle)
  int region = 0;
  float s, sQv = 1.0f;
  if constexpr (EPI == 1) {
    s = *sQp; sQv = *sKp;                 // s_after, s_o
  } else {
    region = (n0 < 4096) ? 0 : ((n0 < 5120) ? 1 : 2);
    s = (region == 0) ? *sQp : (region == 1) ? *sKp : *sVp;
  }

  #pragma unroll
  for (int i = 0; i < MI; ++i)
    #pragma unroll
    for (int j = 0; j < 4; ++j) {
      const int gc = n0 + wn + (j << 4) + lrow;
      #pragma unroll
      for (int r = 0; r < 4; ++r) {
        const int gr = m0 + wm + (i << 4) + ((lane >> 4) << 2) + r;
        float x = acc[i][j][r];
        if constexpr (EPI == 1) {
          C[(size_t)gr * ldc + gc] = lsq_sym(x * s, sQv);
        } else {
          if (region <= 1) {
            float qv = lsq_sym(x, s);
            float pv = __shfl_xor(qv, 1);
            const int dperm = gc & 127;
            const int dpair = dperm >> 1;
            float cs = cosp[(size_t)gr * HD_ + dpair];
            float sn = sinp[(size_t)gr * HD_ + dpair];
            float ro = (gc & 1) ? (qv * cs + pv * sn) : (qv * cs - pv * sn);
            f16pair hp = cvt_hilo(ro);
            if (region == 0) {
              qhi[(size_t)gr * 4096 + gc] = hp.hi;
              qlo[(size_t)gr * 4096 + gc] = hp.lo;
            } else {
              const int lcol = gc - 4096;
              const int bb = gr >> 10, ki = gr & 1023;
              const int kvh = lcol >> 7;
              const int c = dperm >> 5, sub = (dperm >> 3) & 3, e = dperm & 7;
              const size_t base = ((size_t)(bb * 8 + kvh) << 18) + ((size_t)(ki >> 4) << 12)
                                + (c << 10) + ((ki & 15) << 3) + (sub << 7) + e;
              kfrag[base] = hp.hi;
              kfrag[base + 512] = hp.lo;
            }
          } else {
            float xi = rintf(fminf(fmaxf(x / s, -128.0f), 127.0f));
            const int lcol = gc - 5120;
            const int bb = gr >> 10, ss = gr & 1023;
            const int kv = lcol >> 7, dd = lcol & 127;
            vt[(((size_t)(bb * 8 + kv) * 128 + dd) << 10) + ss] = (f16)xi;
          }
        }
      }
    }
}

// ---------------------------------------------------------------------------
// Fused scores+quant+mask+softmax: 16 q-rows/block, 4 waves, swapped mfma(K,Q):
// D[ki][qi], lane -> qi = qi0+(lane&15), ki = tile*16 + (lane>>4)*4 + r.
// K loaded from Kfrag: 1KB contiguous per wave instruction. float4 stores.
// ---------------------------------------------------------------------------
__global__ __launch_bounds__(256)
void attn_fused(const f16* __restrict__ qhiB, const f16* __restrict__ qloB,
                const f16* __restrict__ kfrag, float* __restrict__ attn,
                const float* __restrict__ saP)
{
  const int b = blockIdx.z, h = blockIdx.y, qi0 = blockIdx.x << 4;
  const int t = threadIdx.x, lane = t & 63, w = t >> 6;   // w in 0..3
  const int lc = lane & 15, lg = lane >> 4;
  const int kvh = h >> 2;
  const float sa = *saP;

  f16x8 qh[4], ql[4];
  {
    const size_t qoff = (size_t)(b * S_ + qi0 + lc) * 4096 + h * HD_;
    #pragma unroll
    for (int c = 0; c < 4; ++c) {
      const int off = c * 32 + lg * 8;
      qh[c] = *(const f16x8*)(qhiB + qoff + off);
      ql[c] = *(const f16x8*)(qloB + qoff + off);
    }
  }

  f32x4 acc[16];
  #pragma unroll
  for (int tt = 0; tt < 16; ++tt) acc[tt] = (f32x4){0.f, 0.f, 0.f, 0.f};

  const int qimax = qi0 + 15;
  const f16* kb = kfrag + ((size_t)(b * 8 + kvh) << 18);

  #pragma unroll
  for (int tt = 0; tt < 16; ++tt) {
    const int ki0 = (w << 8) + (tt << 4);
    if (ki0 <= qimax) {
      const f16* kt = kb + ((size_t)((w << 4) + tt) << 12) + lane * 8;
      #pragma unroll
      for (int c = 0; c < 4; ++c) {
        f16x8 kh = *(const f16x8*)(kt + (c << 10));
        f16x8 kl = *(const f16x8*)(kt + (c << 10) + 512);
        acc[tt] = __builtin_amdgcn_mfma_f32_16x16x32_f16(kh, qh[c], acc[tt], 0, 0, 0);
        acc[tt] = __builtin_amdgcn_mfma_f32_16x16x32_f16(kh, ql[c], acc[tt], 0, 0, 0);
        acc[tt] = __builtin_amdgcn_mfma_f32_16x16x32_f16(kl, qh[c], acc[tt], 0, 0, 0);
      }
    }
  }

  const int qi = qi0 + lc;

  float m = -3.0e38f;
  #pragma unroll
  for (int tt = 0; tt < 16; ++tt) {
    const int kib = (w << 8) + (tt << 4) + (lg << 2);
    #pragma unroll
    for (int r = 0; r < 4; ++r) {
      float x = (kib + r <= qi) ? lsq_asym(acc[tt][r] * SCALING, sa) : -3.0e38f;
      acc[tt][r] = x;
      m = fmaxf(m, x);
    }
  }
  m = fmaxf(m, __shfl_xor(m, 16));
  m = fmaxf(m, __shfl_xor(m, 32));

  __shared__ float redM[4][16];
  __shared__ float redS[4][16];
  if (lg == 0) redM[w][lc] = m;
  __syncthreads();
  float mrow = fmaxf(fmaxf(redM[0][lc], redM[1][lc]), fmaxf(redM[2][lc], redM[3][lc]));

  float ssum = 0.f;
  #pragma unroll
  for (int tt = 0; tt < 16; ++tt) {
    #pragma unroll
    for (int r = 0; r < 4; ++r) {
      float p = __expf(acc[tt][r] - mrow);
      acc[tt][r] = p;
      ssum += p;
    }
  }
  ssum += __shfl_xor(ssum, 16);
  ssum += __shfl_xor(ssum, 32);
  if (lg == 0) redS[w][lc] = ssum;
  __syncthreads();
  const float inv = 1.0f / (redS[0][lc] + redS[1][lc] + redS[2][lc] + redS[3][lc]);

  float* orow = attn + ((size_t)(b * NH_ + h) * S_ + qi) * S_ + (w << 8) + (lg << 2);
  #pragma unroll
  for (int tt = 0; tt < 16; ++tt) {
    float4 v;
    v.x = acc[tt][0] * inv;
    v.y = acc[tt][1] * inv;
    v.z = acc[tt][2] * inv;
    v.w = acc[tt][3] * inv;
    *(float4*)(orow + (tt << 4)) = v;
  }
}

// ---------------------------------------------------------------------------
// PV via MFMA: D'[d][q] = sum_ki Vt[d][ki] * P[q][ki]  (= (P·V)^T).
// A = Vt (exact int f16, 1 term); B = P rows, hi/lo split in-regs (2 terms).
// Epilogue: PVint = round(clip(s_v*acc/s_after,0,255)) exact f16, packed [m][4096].
// ---------------------------------------------------------------------------
__global__ __launch_bounds__(256)
void pv_mfma(const float* __restrict__ attn, const f16* __restrict__ vt,
             f16* __restrict__ pvint,
             const float* __restrict__ svP, const float* __restrict__ safP)
{
  const int b = blockIdx.z, h = blockIdx.y, q0 = blockIdx.x << 7;
  const int t = threadIdx.x, lane = t & 63, w = t >> 6;
  const int wd = (w >> 1) << 6, wq = (w & 1) << 6;
  const int lc = lane & 15, lg = lane >> 4;
  const int kvh = h >> 2;
  const float sv = *svP, saf = *safP;

  f32x4 acc[4][4];
  #pragma unroll
  for (int i = 0; i < 4; ++i)
    #pragma unroll
    for (int j = 0; j < 4; ++j) acc[i][j] = (f32x4){0.f, 0.f, 0.f, 0.f};

  const float* Pbase = attn + (size_t)(b * NH_ + h) * S_ * S_;
  const int kimax = q0 + 128;

  for (int ki0 = 0; ki0 < kimax; ki0 += 32) {
    f16x8 a[4];
    #pragma unroll
    for (int i = 0; i < 4; ++i) {
      const int d = wd + i * 16 + lc;
      a[i] = *(const f16x8*)(vt + (((size_t)(b * 8 + kvh) * 128 + d) << 10) + ki0 + lg * 8);
    }
    #pragma unroll
    for (int j = 0; j < 4; ++j) {
      const int q = q0 + wq + j * 16 + lc;
      const float* pp = Pbase + (size_t)q * S_ + ki0 + lg * 8;
      float4 p0 = *(const float4*)pp;
      float4 p1 = *(const float4*)(pp + 4);
      f16x8 bh, bl; f16pair pr;
      pr = cvt_hilo(p0.x); bh[0] = pr.hi; bl[0] = pr.lo;
      pr = cvt_hilo(p0.y); bh[1] = pr.hi; bl[1] = pr.lo;
      pr = cvt_hilo(p0.z); bh[2] = pr.hi; bl[2] = pr.lo;
      pr = cvt_hilo(p0.w); bh[3] = pr.hi; bl[3] = pr.lo;
      pr = cvt_hilo(p1.x); bh[4] = pr.hi; bl[4] = pr.lo;
      pr = cvt_hilo(p1.y); bh[5] = pr.hi; bl[5] = pr.lo;
      pr = cvt_hilo(p1.z); bh[6] = pr.hi; bl[6] = pr.lo;
      pr = cvt_hilo(p1.w); bh[7] = pr.hi; bl[7] = pr.lo;
      #pragma unroll
      for (int i = 0; i < 4; ++i) {
        acc[i][j] = __builtin_amdgcn_mfma_f32_16x16x32_f16(a[i], bh, acc[i][j], 0, 0, 0);
        acc[i][j] = __builtin_amdgcn_mfma_f32_16x16x32_f16(a[i], bl, acc[i][j], 0, 0, 0);
      }
    }
  }

  #pragma unroll
  for (int i = 0; i < 4; ++i)
    #pragma unroll
    for (int j = 0; j < 4; ++j) {
      const int q  = q0 + wq + j * 16 + lc;
      const int d0 = wd + i * 16 + lg * 4;
      f16x4 v;
      #pragma unroll
      for (int r = 0; r < 4; ++r) {
        float x = sv * acc[i][j][r];
        x = fminf(fmaxf(x / saf, 0.0f), 255.0f);
        v[r] = (f16)rintf(x);
      }
      *(f16x4*)(pvint + (size_t)(b * S_ + q) * 4096 + h * HD_ + d0) = v;
    }
}

extern "C" void kernel_launch(void* const* d_in, const int* in_sizes, int n_in,
                              void* d_out, int out_size, void* d_ws, size_t ws_size,
                              hipStream_t stream)
{
  const float* hidden = (const float*)d_in[0];
  const float* cosp   = (const float*)d_in[1];
  const float* sinp   = (const float*)d_in[2];
  const float* Wq     = (const float*)d_in[4];
  const float* Wk     = (const float*)d_in[5];
  const float* Wv     = (const float*)d_in[6];
  const float* Wo     = (const float*)d_in[7];
  const float* s_q    = (const float*)d_in[8];
  const float* s_k    = (const float*)d_in[9];
  const float* s_v    = (const float*)d_in[10];
  const float* s_attn = (const float*)d_in[11];
  const float* s_after= (const float*)d_in[12];
  const float* s_o    = (const float*)d_in[13];

  float* out  = (float*)d_out;                 // (B,S,H) f32
  float* attn = out + (size_t)M_ * H_;         // (B,NH,S,S) f32 — written by attn_fused

  f16* wsf   = (f16*)d_ws;
  f16* Qhi   = wsf;                    // [0,16M)
  f16* Qlo   = wsf + (size_t)R16M;     // [16M,32M)
  f16* Kfrag = wsf + (size_t)2*R16M;   // [32M,40M)
  f16* Vt    = wsf + (size_t)2*R16M + (size_t)R16M/2;  // [40M,44M)
  f16* PVint = wsf;                    // alias Qhi (dead after attn)
  f16* WoHi  = wsf + (size_t)R16M;     // alias Qlo
  f16* WoLo  = wsf + (size_t)2*R16M;   // alias Kfrag/Vt/spare

  // split scratch inside the not-yet-written attn region (~168 MB of 537)
  f16* scr = (f16*)attn;
  f16* hHi   = scr;                                  // hidden hi [0,16M)
  f16* hLo   = scr + (size_t)R16M;                   // hidden lo
  f16* WcatH = scr + (size_t)2*R16M;                 // [6144][4096] hi (24M f16)
  f16* WcatL = scr + (size_t)2*R16M + (size_t)6144*4096;  // lo

  dim3 blk(256, 1, 1);

  // 1) splits: hidden; Wq (rope-perm) -> rows [0,4096); Wk (rope-perm) -> rows
  //    [4096,5120); Wv (plain) -> rows [5120,6144) of Wcat
  split_flat<<<dim3(16384), blk, 0, stream>>>(hidden, hHi, hLo);
  split_wqk <<<dim3(16384), blk, 0, stream>>>(Wq, WcatH, WcatL);
  split_wqk <<<dim3(4096),  blk, 0, stream>>>(Wk, WcatH + (size_t)4096*4096, WcatL + (size_t)4096*4096);
  split_flat<<<dim3(4096),  blk, 0, stream>>>(Wv, WcatH + (size_t)5120*4096, WcatL + (size_t)5120*4096);

  // 2) ONE fused QKV projection GEMM (128^2 tiles, counted-vmcnt pipeline + setprio)
  gemm_mfma<128,2,5><<<dim3(48,32), blk, 0, stream>>>(hHi, hLo, H_, WcatH, WcatL, H_,
      nullptr, 0, H_, s_q, s_k, s_v, cosp, sinp, Qhi, Qlo, Kfrag, Vt);

  // 3) fused scores+quant+mask+softmax -> probs straight to d_out
  attn_fused<<<dim3(64, NH_, B_), blk, 0, stream>>>(Qhi, Qlo, Kfrag, attn, s_attn);

  // 4) PV (MFMA) -> PVint packed [m][4096]
  pv_mfma<<<dim3(8, NH_, B_), blk, 0, stream>>>(attn, Vt, PVint, s_v, s_after);

  // 5) Wo split (packed); final GEMM (256x128 tiles — r17 best config)
  split_flat<<<dim3(16384), blk, 0, stream>>>(Wo, WoHi, WoLo);
  gemm_mfma<256,1,1><<<dim3(32,16), blk, 0, stream>>>(PVint, nullptr, 4096,
      WoHi, WoLo, 4096, out, H_, H_, s_after, s_o, nullptr, nullptr, nullptr,
      nullptr, nullptr, nullptr, nullptr);
}